// Round 3
// baseline (2369.396 us; speedup 1.0000x reference)
//
#include <hip/hip_runtime.h>
#include <math.h>

#define T_TOK 32768
#define D_DIM 128
#define K_CODE 8192
#define KSPLIT 4
#define KPER (K_CODE / KSPLIT)

// Pin a float into a VGPR: compiler cannot rematerialize/reload past this.
#define PIN(x) asm volatile("" : "+v"(x))

// ---------------- proj: C[r][c] = sum_d E[r][d]*W[c][d] + b[c] ----------------
__global__ __launch_bounds__(256) void proj_kernel(const float* __restrict__ E,
                                                   const float* __restrict__ W,
                                                   const float* __restrict__ b,
                                                   float* __restrict__ C) {
    int idx = blockIdx.x * 256 + threadIdx.x;   // r*128 + c
    int r = idx >> 7, c = idx & 127;
    const float4* E4 = (const float4*)(E + (size_t)r * D_DIM);
    const float4* W4 = (const float4*)(W + (size_t)c * D_DIM);
    float4 acc = make_float4(0.f, 0.f, 0.f, 0.f);
#pragma unroll
    for (int dd = 0; dd < 32; ++dd) {
        float4 e = E4[dd], w = W4[dd];
        acc.x = fmaf(e.x, w.x, acc.x);
        acc.y = fmaf(e.y, w.y, acc.y);
        acc.z = fmaf(e.z, w.z, acc.z);
        acc.w = fmaf(e.w, w.w, acc.w);
    }
    C[idx] = ((acc.x + acc.y) + (acc.z + acc.w)) + b[c];
}

// ---------------- cnorm: |c_k|^2 ----------------
__global__ __launch_bounds__(64) void cnorm_kernel(const float* __restrict__ C,
                                                   float* __restrict__ cn) {
    int r = blockIdx.x;
    int l = threadIdx.x;
    float a = C[r * D_DIM + l];
    float b2 = C[r * D_DIM + 64 + l];
    float s = a * a + b2 * b2;
#pragma unroll
    for (int off = 32; off > 0; off >>= 1) s += __shfl_down(s, off, 64);
    if (l == 0) cn[r] = s;
}

// ---------------- argmin over a K-split, one token per lane ----------------
// z is held in 128 pinned VGPRs (R2 failure: compiler rematerialized z loads
// from L1/L2 every k-group -> ~34 GB cache traffic -> VALUBusy 46%).
__global__ __launch_bounds__(256, 2) void argmin_kernel(const float* __restrict__ Z,
                                                        const float* __restrict__ C,
                                                        const float* __restrict__ cn,
                                                        float* __restrict__ bv,
                                                        int* __restrict__ bi) {
    int t = blockIdx.x * 256 + threadIdx.x;
    int split = blockIdx.y;

    const float4* Z4 = (const float4*)(Z + (size_t)t * D_DIM);
    float zr[D_DIM];
#pragma unroll
    for (int dd = 0; dd < 32; ++dd) {
        float4 z4 = Z4[dd];
        zr[4 * dd + 0] = z4.x;
        zr[4 * dd + 1] = z4.y;
        zr[4 * dd + 2] = z4.z;
        zr[4 * dd + 3] = z4.w;
    }

    float zn = 0.f;
#pragma unroll
    for (int d = 0; d < D_DIM; ++d) zn += zr[d] * zr[d];

    // Force all 128 z values (and zn) to live in VGPRs for the whole k-loop.
#pragma unroll
    for (int d = 0; d < D_DIM; ++d) PIN(zr[d]);
    PIN(zn);

    const float4* C4 = (const float4*)C;
    float best = 3.4e38f;
    int bidx = split * KPER;

    int k0 = split * KPER;
    for (int k = k0; k < k0 + KPER; k += 4) {
        const float4* cA = C4 + (size_t)k * 32;
        const float4* cB = cA + 32;
        const float4* cC = cA + 64;
        const float4* cD = cA + 96;
        float d0 = 0.f, d1 = 0.f, d2 = 0.f, d3 = 0.f;
#pragma unroll
        for (int dd = 0; dd < 32; ++dd) {
            float4 a = cA[dd], b = cB[dd], c = cC[dd], e = cD[dd];
            d0 = fmaf(zr[4 * dd + 0], a.x, d0);
            d1 = fmaf(zr[4 * dd + 0], b.x, d1);
            d2 = fmaf(zr[4 * dd + 0], c.x, d2);
            d3 = fmaf(zr[4 * dd + 0], e.x, d3);
            d0 = fmaf(zr[4 * dd + 1], a.y, d0);
            d1 = fmaf(zr[4 * dd + 1], b.y, d1);
            d2 = fmaf(zr[4 * dd + 1], c.y, d2);
            d3 = fmaf(zr[4 * dd + 1], e.y, d3);
            d0 = fmaf(zr[4 * dd + 2], a.z, d0);
            d1 = fmaf(zr[4 * dd + 2], b.z, d1);
            d2 = fmaf(zr[4 * dd + 2], c.z, d2);
            d3 = fmaf(zr[4 * dd + 2], e.z, d3);
            d0 = fmaf(zr[4 * dd + 3], a.w, d0);
            d1 = fmaf(zr[4 * dd + 3], b.w, d1);
            d2 = fmaf(zr[4 * dd + 3], c.w, d2);
            d3 = fmaf(zr[4 * dd + 3], e.w, d3);
        }
        // Match reference rounding: (|z|^2 + |c|^2) - 2*dot, elementwise fp32.
        float s0 = (zn + cn[k + 0]) - 2.f * d0;
        float s1 = (zn + cn[k + 1]) - 2.f * d1;
        float s2 = (zn + cn[k + 2]) - 2.f * d2;
        float s3 = (zn + cn[k + 3]) - 2.f * d3;
        if (s0 < best) { best = s0; bidx = k + 0; }
        if (s1 < best) { best = s1; bidx = k + 1; }
        if (s2 < best) { best = s2; bidx = k + 2; }
        if (s3 < best) { best = s3; bidx = k + 3; }
    }
    bv[(size_t)split * T_TOK + t] = best;
    bi[(size_t)split * T_TOK + t] = bidx;
}

// ---------------- merge splits, histogram counts ----------------
__global__ __launch_bounds__(256) void merge_kernel(const float* __restrict__ bv,
                                                    const int* __restrict__ bi,
                                                    int* __restrict__ idxf,
                                                    int* __restrict__ counts) {
    int t = blockIdx.x * 256 + threadIdx.x;
    float best = bv[t];
    int idx = bi[t];
#pragma unroll
    for (int s = 1; s < KSPLIT; ++s) {
        float v = bv[(size_t)s * T_TOK + t];
        int i2 = bi[(size_t)s * T_TOK + t];
        if (v < best) { best = v; idx = i2; }
    }
    idxf[t] = idx;
    atomicAdd(&counts[idx], 1);
}

// ---------------- gather z_q, write z_q_st, accumulate commit-loss sum ----------------
__global__ __launch_bounds__(256) void zq_kernel(const float* __restrict__ Z,
                                                 const float* __restrict__ C,
                                                 const int* __restrict__ idxf,
                                                 float* __restrict__ out,
                                                 float* __restrict__ loss) {
    int gid = blockIdx.x * 256 + threadIdx.x;   // over T*D/4 = 1048576 float4s
    int t = gid >> 5;                           // 32 float4 per token
    int d4 = gid & 31;
    int idx = idxf[t];
    float4 cv = ((const float4*)C)[(size_t)idx * 32 + d4];
    float4 zv = ((const float4*)Z)[gid];
    float dx = cv.x - zv.x, dy = cv.y - zv.y, dz = cv.z - zv.z, dw = cv.w - zv.w;
    float4 o;
    o.x = zv.x + dx;    // z + (z_q - z): match reference elementwise rounding
    o.y = zv.y + dy;
    o.z = zv.z + dz;
    o.w = zv.w + dw;
    ((float4*)out)[gid] = o;

    float ls = dx * dx + dy * dy + dz * dz + dw * dw;
#pragma unroll
    for (int off = 32; off > 0; off >>= 1) ls += __shfl_down(ls, off, 64);
    __shared__ float red[4];
    int lane = threadIdx.x & 63, w = threadIdx.x >> 6;
    if (lane == 0) red[w] = ls;
    __syncthreads();
    if (threadIdx.x == 0) {
        atomicAdd(loss, (red[0] + red[1]) + (red[2] + red[3]));
    }
}

// ---------------- scalars: commit_loss, perplexity ----------------
__global__ __launch_bounds__(256) void scalars_kernel(const int* __restrict__ counts,
                                                      const float* __restrict__ loss,
                                                      float* __restrict__ out) {
    float s = 0.f;
    for (int i = threadIdx.x; i < K_CODE; i += 256) {
        float e = (float)counts[i] * (1.0f / (float)T_TOK);
        s += e * logf(e + 1e-8f);
    }
#pragma unroll
    for (int off = 32; off > 0; off >>= 1) s += __shfl_down(s, off, 64);
    __shared__ float red[4];
    int lane = threadIdx.x & 63, w = threadIdx.x >> 6;
    if (lane == 0) red[w] = s;
    __syncthreads();
    if (threadIdx.x == 0) {
        float ssum = (red[0] + red[1]) + (red[2] + red[3]);
        out[(size_t)T_TOK * D_DIM + 0] = 1.25f * loss[0] / (float)((size_t)T_TOK * D_DIM);
        out[(size_t)T_TOK * D_DIM + 1] = expf(-ssum);
    }
}

extern "C" void kernel_launch(void* const* d_in, const int* in_sizes, int n_in,
                              void* d_out, int out_size, void* d_ws, size_t ws_size,
                              hipStream_t stream) {
    const float* z   = (const float*)d_in[0];   // [8,4096,128]
    const float* emb = (const float*)d_in[1];   // [8192,128]
    const float* pw  = (const float*)d_in[2];   // [128,128]
    const float* pb  = (const float*)d_in[3];   // [128]
    float* out = (float*)d_out;

    char* ws = (char*)d_ws;
    float* C      = (float*)(ws + 0);
    float* cn     = (float*)(ws + 4194304);
    float* bv     = (float*)(ws + 4227072);
    int*   bi     = (int*)  (ws + 4751360);
    int*   idxf   = (int*)  (ws + 5275648);
    int*   counts = (int*)  (ws + 5406720);
    float* loss   = (float*)(ws + 5439488);

    hipMemsetAsync(ws + 5406720, 0, 32768 + 4, stream);   // counts + loss

    proj_kernel<<<(K_CODE * D_DIM) / 256, 256, 0, stream>>>(emb, pw, pb, C);
    cnorm_kernel<<<K_CODE, 64, 0, stream>>>(C, cn);
    argmin_kernel<<<dim3(T_TOK / 256, KSPLIT), 256, 0, stream>>>(z, C, cn, bv, bi);
    merge_kernel<<<T_TOK / 256, 256, 0, stream>>>(bv, bi, idxf, counts);
    zq_kernel<<<(T_TOK * D_DIM / 4) / 256, 256, 0, stream>>>(z, C, idxf, out, loss);
    scalars_kernel<<<1, 256, 0, stream>>>(counts, loss, out);
}

// Round 4
// 1221.443 us; speedup vs baseline: 1.9398x; 1.9398x over previous
//
#include <hip/hip_runtime.h>
#include <math.h>

#define T_TOK 32768
#define D_DIM 128
#define K_CODE 8192
#define BM 256              // tokens per block
#define BN 64               // codes per block
#define BK 32               // k chunk
#define NSPLIT (K_CODE / BN)

typedef unsigned long long ull;

// ---------------- proj: C[r][c] = sum_d E[r][d]*W[c][d] + b[c] ----------------
__global__ __launch_bounds__(256) void proj_kernel(const float* __restrict__ E,
                                                   const float* __restrict__ W,
                                                   const float* __restrict__ b,
                                                   float* __restrict__ C) {
    int idx = blockIdx.x * 256 + threadIdx.x;   // r*128 + c
    int r = idx >> 7, c = idx & 127;
    const float4* E4 = (const float4*)(E + (size_t)r * D_DIM);
    const float4* W4 = (const float4*)(W + (size_t)c * D_DIM);
    float4 acc = make_float4(0.f, 0.f, 0.f, 0.f);
#pragma unroll
    for (int dd = 0; dd < 32; ++dd) {
        float4 e = E4[dd], w = W4[dd];
        acc.x = fmaf(e.x, w.x, acc.x);
        acc.y = fmaf(e.y, w.y, acc.y);
        acc.z = fmaf(e.z, w.z, acc.z);
        acc.w = fmaf(e.w, w.w, acc.w);
    }
    C[idx] = ((acc.x + acc.y) + (acc.z + acc.w)) + b[c];
}

// ---------------- cnorm: |c_k|^2 ----------------
__global__ __launch_bounds__(64) void cnorm_kernel(const float* __restrict__ C,
                                                   float* __restrict__ cn) {
    int r = blockIdx.x;
    int l = threadIdx.x;
    float a = C[r * D_DIM + l];
    float b2 = C[r * D_DIM + 64 + l];
    float s = a * a + b2 * b2;
#pragma unroll
    for (int off = 32; off > 0; off >>= 1) s += __shfl_down(s, off, 64);
    if (l == 0) cn[r] = s;
}

// ---------------- znorm: |z_t|^2 ----------------
__global__ __launch_bounds__(64) void znorm_kernel(const float* __restrict__ Z,
                                                   float* __restrict__ zn) {
    int t = blockIdx.x;
    int l = threadIdx.x;
    float a = Z[(size_t)t * D_DIM + l];
    float b2 = Z[(size_t)t * D_DIM + 64 + l];
    float s = a * a + b2 * b2;
#pragma unroll
    for (int off = 32; off > 0; off >>= 1) s += __shfl_down(s, off, 64);
    if (l == 0) zn[t] = s;
}

// ---------------- GEMM-style argmin ----------------
// Big register state = accumulators (compiler cannot demote). z tile in LDS
// (transposed, conflict-free b128 reads). Codebook fragment is wave-uniform ->
// scalar loads (s_load), zero LDS traffic for B.
__global__ __launch_bounds__(256, 4) void argmin_kernel(const float* __restrict__ Z,
                                                        const float* __restrict__ C,
                                                        const float* __restrict__ cn,
                                                        const float* __restrict__ zn,
                                                        ull* __restrict__ packed) {
    __shared__ float As[BK][BM + 4];   // 32 x 260 floats = 33280 B

    int tid = threadIdx.x;
    int lane = tid & 63;
    int wid = __builtin_amdgcn_readfirstlane(tid >> 6);   // force wave-uniform
    int mb = blockIdx.x * BM;
    int n0 = blockIdx.y * BN + wid * 16;

    float acc[4][16];
#pragma unroll
    for (int i = 0; i < 4; ++i)
#pragma unroll
        for (int j = 0; j < 16; ++j) acc[i][j] = 0.f;

    const float4* Z4 = (const float4*)Z;

    for (int kc = 0; kc < D_DIM / BK; ++kc) {
        // ---- stage As[k][m] (transposed) ----
#pragma unroll
        for (int j = 0; j < 8; ++j) {
            int idx = j * 256 + tid;        // 0..2047
            int m = idx >> 3;               // token 0..255
            int f4 = idx & 7;               // float4 within the 32-k chunk
            float4 v = Z4[(size_t)(mb + m) * 32 + kc * 8 + f4];
            As[4 * f4 + 0][m] = v.x;
            As[4 * f4 + 1][m] = v.y;
            As[4 * f4 + 2][m] = v.z;
            As[4 * f4 + 3][m] = v.w;
        }
        __syncthreads();
        // ---- compute ----
#pragma unroll 4
        for (int k = 0; k < BK; ++k) {
            int kg = kc * BK + k;
            float4 av = *(const float4*)&As[k][4 * lane];
#pragma unroll
            for (int j = 0; j < 16; ++j) {
                float bj = C[(size_t)(n0 + j) * D_DIM + kg];   // uniform -> s_load
                acc[0][j] = fmaf(av.x, bj, acc[0][j]);
                acc[1][j] = fmaf(av.y, bj, acc[1][j]);
                acc[2][j] = fmaf(av.z, bj, acc[2][j]);
                acc[3][j] = fmaf(av.w, bj, acc[3][j]);
            }
        }
        __syncthreads();
    }

    // ---- epilogue: per-token argmin over this block's 64 codes ----
    int t0 = mb + 4 * lane;
    float4 znv = *(const float4*)&zn[t0];
    float zni[4] = {znv.x, znv.y, znv.z, znv.w};

    float* rbest = &As[0][0];                 // reuse LDS: 1024 floats
    int*   ridx  = (int*)(&As[0][0]) + 1024;  // 1024 ints

#pragma unroll
    for (int i = 0; i < 4; ++i) {
        float best = 3.4e38f;
        int bidx = n0;
#pragma unroll
        for (int j = 0; j < 16; ++j) {
            // Match reference rounding: (|z|^2 + |c|^2) - 2*dot, elementwise fp32.
            float s = (zni[i] + cn[n0 + j]) - 2.f * acc[i][j];
            if (s < best) { best = s; bidx = n0 + j; }
        }
        rbest[(4 * lane + i) * 4 + wid] = best;
        ridx[(4 * lane + i) * 4 + wid] = bidx;
    }
    __syncthreads();

    // one token per thread: reduce the 4 waves (ascending wid = ascending code)
    {
        float best = rbest[tid * 4 + 0];
        int bidx = ridx[tid * 4 + 0];
#pragma unroll
        for (int w = 1; w < 4; ++w) {
            float v = rbest[tid * 4 + w];
            int i2 = ridx[tid * 4 + w];
            if (v < best) { best = v; bidx = i2; }
        }
        // d > 0 always (d ~ 100..170), so f32 bits are monotone as uint.
        // idx in low bits -> ties resolve to smallest idx (first-min).
        ull pk = ((ull)__float_as_uint(best) << 32) | (unsigned)bidx;
        atomicMin(&packed[mb + tid], pk);
    }
}

// ---------------- merge: unpack winner, histogram counts ----------------
__global__ __launch_bounds__(256) void merge_kernel(const ull* __restrict__ packed,
                                                    int* __restrict__ idxf,
                                                    int* __restrict__ counts) {
    int t = blockIdx.x * 256 + threadIdx.x;
    int idx = (int)(packed[t] & 0xFFFFFFFFull);
    idxf[t] = idx;
    atomicAdd(&counts[idx], 1);
}

// ---------------- gather z_q, write z_q_st, accumulate commit-loss sum ----------------
__global__ __launch_bounds__(256) void zq_kernel(const float* __restrict__ Z,
                                                 const float* __restrict__ C,
                                                 const int* __restrict__ idxf,
                                                 float* __restrict__ out,
                                                 float* __restrict__ loss) {
    int gid = blockIdx.x * 256 + threadIdx.x;   // over T*D/4 float4s
    int t = gid >> 5;                           // 32 float4 per token
    int d4 = gid & 31;
    int idx = idxf[t];
    float4 cv = ((const float4*)C)[(size_t)idx * 32 + d4];
    float4 zv = ((const float4*)Z)[gid];
    float dx = cv.x - zv.x, dy = cv.y - zv.y, dz = cv.z - zv.z, dw = cv.w - zv.w;
    float4 o;
    o.x = zv.x + dx;    // z + (z_q - z): match reference elementwise rounding
    o.y = zv.y + dy;
    o.z = zv.z + dz;
    o.w = zv.w + dw;
    ((float4*)out)[gid] = o;

    float ls = dx * dx + dy * dy + dz * dz + dw * dw;
#pragma unroll
    for (int off = 32; off > 0; off >>= 1) ls += __shfl_down(ls, off, 64);
    __shared__ float red[4];
    int lane = threadIdx.x & 63, w = threadIdx.x >> 6;
    if (lane == 0) red[w] = ls;
    __syncthreads();
    if (threadIdx.x == 0) {
        atomicAdd(loss, (red[0] + red[1]) + (red[2] + red[3]));
    }
}

// ---------------- scalars: commit_loss, perplexity ----------------
__global__ __launch_bounds__(256) void scalars_kernel(const int* __restrict__ counts,
                                                      const float* __restrict__ loss,
                                                      float* __restrict__ out) {
    float s = 0.f;
    for (int i = threadIdx.x; i < K_CODE; i += 256) {
        float e = (float)counts[i] * (1.0f / (float)T_TOK);
        s += e * logf(e + 1e-8f);
    }
#pragma unroll
    for (int off = 32; off > 0; off >>= 1) s += __shfl_down(s, off, 64);
    __shared__ float red[4];
    int lane = threadIdx.x & 63, w = threadIdx.x >> 6;
    if (lane == 0) red[w] = s;
    __syncthreads();
    if (threadIdx.x == 0) {
        float ssum = (red[0] + red[1]) + (red[2] + red[3]);
        out[(size_t)T_TOK * D_DIM + 0] = 1.25f * loss[0] / (float)((size_t)T_TOK * D_DIM);
        out[(size_t)T_TOK * D_DIM + 1] = expf(-ssum);
    }
}

extern "C" void kernel_launch(void* const* d_in, const int* in_sizes, int n_in,
                              void* d_out, int out_size, void* d_ws, size_t ws_size,
                              hipStream_t stream) {
    const float* z   = (const float*)d_in[0];   // [8,4096,128]
    const float* emb = (const float*)d_in[1];   // [8192,128]
    const float* pw  = (const float*)d_in[2];   // [128,128]
    const float* pb  = (const float*)d_in[3];   // [128]
    float* out = (float*)d_out;

    char* ws = (char*)d_ws;
    // layout (bytes):
    //   C:      0        .. 4194304   (8192*128 f32)
    //   cn:     4194304  .. 4227072   (8192 f32)
    //   zn:     4227072  .. 4358144   (32768 f32)
    //   packed: 4358144  .. 4620288   (32768 u64)
    //   idxf:   4620288  .. 4751360   (32768 i32)
    //   counts: 4751360  .. 4784128   (8192 i32)
    //   loss:   4784128  .. 4784132   (1 f32)
    float* C      = (float*)(ws + 0);
    float* cn     = (float*)(ws + 4194304);
    float* zn     = (float*)(ws + 4227072);
    ull*   packed = (ull*)  (ws + 4358144);
    int*   idxf   = (int*)  (ws + 4620288);
    int*   counts = (int*)  (ws + 4751360);
    float* loss   = (float*)(ws + 4784128);

    hipMemsetAsync(packed, 0xFF, (size_t)T_TOK * 8, stream);
    hipMemsetAsync(counts, 0, K_CODE * 4 + 4, stream);   // counts + loss

    proj_kernel<<<(K_CODE * D_DIM) / 256, 256, 0, stream>>>(emb, pw, pb, C);
    cnorm_kernel<<<K_CODE, 64, 0, stream>>>(C, cn);
    znorm_kernel<<<T_TOK, 64, 0, stream>>>(z, zn);
    argmin_kernel<<<dim3(T_TOK / BM, NSPLIT), 256, 0, stream>>>(z, C, cn, zn, packed);
    merge_kernel<<<T_TOK / 256, 256, 0, stream>>>(packed, idxf, counts);
    zq_kernel<<<(T_TOK * D_DIM / 4) / 256, 256, 0, stream>>>(z, C, idxf, out, loss);
    scalars_kernel<<<1, 256, 0, stream>>>(counts, loss, out);
}

// Round 5
// 1089.553 us; speedup vs baseline: 2.1746x; 1.1210x over previous
//
#include <hip/hip_runtime.h>
#include <math.h>

#define T_TOK 32768
#define D_DIM 128
#define K_CODE 8192
#define BM 256              // tokens per block
#define BN 64               // codes per block
#define BK 32               // k chunk
#define NSPLIT (K_CODE / BN)

typedef unsigned long long ull;

// ---------------- proj: C[r][c] = sum_d E[r][d]*W[c][d] + b[c] ----------------
__global__ __launch_bounds__(256) void proj_kernel(const float* __restrict__ E,
                                                   const float* __restrict__ W,
                                                   const float* __restrict__ b,
                                                   float* __restrict__ C) {
    int idx = blockIdx.x * 256 + threadIdx.x;   // r*128 + c
    int r = idx >> 7, c = idx & 127;
    const float4* E4 = (const float4*)(E + (size_t)r * D_DIM);
    const float4* W4 = (const float4*)(W + (size_t)c * D_DIM);
    float4 acc = make_float4(0.f, 0.f, 0.f, 0.f);
#pragma unroll
    for (int dd = 0; dd < 32; ++dd) {
        float4 e = E4[dd], w = W4[dd];
        acc.x = fmaf(e.x, w.x, acc.x);
        acc.y = fmaf(e.y, w.y, acc.y);
        acc.z = fmaf(e.z, w.z, acc.z);
        acc.w = fmaf(e.w, w.w, acc.w);
    }
    C[idx] = ((acc.x + acc.y) + (acc.z + acc.w)) + b[c];
}

// ---------------- cnorm: |c_k|^2 ----------------
__global__ __launch_bounds__(64) void cnorm_kernel(const float* __restrict__ C,
                                                   float* __restrict__ cn) {
    int r = blockIdx.x;
    int l = threadIdx.x;
    float a = C[r * D_DIM + l];
    float b2 = C[r * D_DIM + 64 + l];
    float s = a * a + b2 * b2;
#pragma unroll
    for (int off = 32; off > 0; off >>= 1) s += __shfl_down(s, off, 64);
    if (l == 0) cn[r] = s;
}

// ---------------- znorm: |z_t|^2 ----------------
__global__ __launch_bounds__(64) void znorm_kernel(const float* __restrict__ Z,
                                                   float* __restrict__ zn) {
    int t = blockIdx.x;
    int l = threadIdx.x;
    float a = Z[(size_t)t * D_DIM + l];
    float b2 = Z[(size_t)t * D_DIM + 64 + l];
    float s = a * a + b2 * b2;
#pragma unroll
    for (int off = 32; off > 0; off >>= 1) s += __shfl_down(s, off, 64);
    if (l == 0) zn[t] = s;
}

// ---------------- GEMM-style argmin, both tiles in LDS ----------------
// R4 lessons: (1) per-k s_loads of C force lgkmcnt(0) (SMEM is OOO) and kill
// pipelining -> B now staged in LDS, read via same-address broadcast b128
// (DS is in-order -> fine-grained lgkmcnt). (2) A-staging + epilogue LDS
// patterns re-mapped to lane-consecutive banks (conflict-free).
__global__ __launch_bounds__(256, 3) void argmin_kernel(const float* __restrict__ Z,
                                                        const float* __restrict__ C,
                                                        const float* __restrict__ cn,
                                                        const float* __restrict__ zn,
                                                        ull* __restrict__ packed) {
    __shared__ float As[BK][BM + 4];   // 32 x 260 floats = 33280 B
    __shared__ float Bs[BK][BN + 4];   // 32 x 68 floats  =  8704 B

    int tid = threadIdx.x;
    int lane = tid & 63;
    int wid = __builtin_amdgcn_readfirstlane(tid >> 6);
    int mb = blockIdx.x * BM;
    int nb = blockIdx.y * BN;
    int n0 = nb + wid * 16;

    float acc[4][16];
#pragma unroll
    for (int i = 0; i < 4; ++i)
#pragma unroll
        for (int j = 0; j < 16; ++j) acc[i][j] = 0.f;

    const float4* Z4 = (const float4*)Z;
    const float4* C4 = (const float4*)C;

    for (int kc = 0; kc < D_DIM / BK; ++kc) {
        // ---- stage As[k][m]: thread -> token tid, k-chunk j ----
        // write bank = (4*(4j+c) + tid) % 32: lane-consecutive -> conflict-free
#pragma unroll
        for (int j = 0; j < 8; ++j) {
            float4 v = Z4[(size_t)(mb + tid) * 32 + kc * 8 + j];
            As[4 * j + 0][tid] = v.x;
            As[4 * j + 1][tid] = v.y;
            As[4 * j + 2][tid] = v.z;
            As[4 * j + 3][tid] = v.w;
        }
        // ---- stage Bs[k][n] (transposed from C[code][d]) ----
#pragma unroll
        for (int it = 0; it < 2; ++it) {
            int idx = it * 256 + tid;       // 0..511
            int n = idx & 63;               // code within block
            int f4 = idx >> 6;              // k-chunk float4 0..7
            float4 v = C4[(size_t)(nb + n) * 32 + kc * 8 + f4];
            Bs[4 * f4 + 0][n] = v.x;
            Bs[4 * f4 + 1][n] = v.y;
            Bs[4 * f4 + 2][n] = v.z;
            Bs[4 * f4 + 3][n] = v.w;
        }
        __syncthreads();
        // ---- compute: per k, 1 b128 A-frag + 4 broadcast b128 B-frags ----
#pragma unroll 4
        for (int k = 0; k < BK; ++k) {
            float4 av = *(const float4*)&As[k][4 * lane];
            float4 b0 = *(const float4*)&Bs[k][wid * 16 + 0];
            float4 b1 = *(const float4*)&Bs[k][wid * 16 + 4];
            float4 b2 = *(const float4*)&Bs[k][wid * 16 + 8];
            float4 b3 = *(const float4*)&Bs[k][wid * 16 + 12];
            float bj[16] = {b0.x, b0.y, b0.z, b0.w, b1.x, b1.y, b1.z, b1.w,
                            b2.x, b2.y, b2.z, b2.w, b3.x, b3.y, b3.z, b3.w};
#pragma unroll
            for (int j = 0; j < 16; ++j) {
                acc[0][j] = fmaf(av.x, bj[j], acc[0][j]);
                acc[1][j] = fmaf(av.y, bj[j], acc[1][j]);
                acc[2][j] = fmaf(av.z, bj[j], acc[2][j]);
                acc[3][j] = fmaf(av.w, bj[j], acc[3][j]);
            }
        }
        __syncthreads();
    }

    // ---- epilogue: per-token argmin over this block's 64 codes ----
    int t0 = mb + 4 * lane;
    float4 znv = *(const float4*)&zn[t0];
    float zni[4] = {znv.x, znv.y, znv.z, znv.w};

    // reuse As: rb[4][260] floats then ri[4][260] ints (both 16B-aligned)
    float* rb = &As[0][0];
    int*   ri = (int*)(&As[0][0]) + 4 * (BM + 4);

    float bb[4];
    int   bi4[4];
#pragma unroll
    for (int i = 0; i < 4; ++i) {
        float best = 3.4e38f;
        int bidx = n0;
#pragma unroll
        for (int j = 0; j < 16; ++j) {
            // Match reference rounding: (|z|^2 + |c|^2) - 2*dot, elementwise fp32.
            float s = (zni[i] + cn[n0 + j]) - 2.f * acc[i][j];
            if (s < best) { best = s; bidx = n0 + j; }
        }
        bb[i] = best;
        bi4[i] = bidx;
    }
    // conflict-free: float4 per lane into row wid
    *(float4*)&rb[wid * (BM + 4) + 4 * lane] = make_float4(bb[0], bb[1], bb[2], bb[3]);
    *(int4*)&ri[wid * (BM + 4) + 4 * lane] = make_int4(bi4[0], bi4[1], bi4[2], bi4[3]);
    __syncthreads();

    // one token per thread: reduce the 4 waves (ascending wid = ascending code)
    {
        float best = rb[0 * (BM + 4) + tid];
        int bidx = ri[0 * (BM + 4) + tid];
#pragma unroll
        for (int w = 1; w < 4; ++w) {
            float v = rb[w * (BM + 4) + tid];
            int i2 = ri[w * (BM + 4) + tid];
            if (v < best) { best = v; bidx = i2; }
        }
        // d > 0 always (d ~ 100..170), so f32 bits are monotone as uint.
        // idx in low bits -> ties resolve to smallest idx (first-min).
        ull pk = ((ull)__float_as_uint(best) << 32) | (unsigned)bidx;
        atomicMin(&packed[mb + tid], pk);
    }
}

// ---------------- merge: unpack winner, histogram counts ----------------
__global__ __launch_bounds__(256) void merge_kernel(const ull* __restrict__ packed,
                                                    int* __restrict__ idxf,
                                                    int* __restrict__ counts) {
    int t = blockIdx.x * 256 + threadIdx.x;
    int idx = (int)(packed[t] & 0xFFFFFFFFull);
    idxf[t] = idx;
    atomicAdd(&counts[idx], 1);
}

// ---------------- gather z_q, write z_q_st, accumulate commit-loss sum ----------------
__global__ __launch_bounds__(256) void zq_kernel(const float* __restrict__ Z,
                                                 const float* __restrict__ C,
                                                 const int* __restrict__ idxf,
                                                 float* __restrict__ out,
                                                 float* __restrict__ loss) {
    int gid = blockIdx.x * 256 + threadIdx.x;   // over T*D/4 float4s
    int t = gid >> 5;                           // 32 float4 per token
    int d4 = gid & 31;
    int idx = idxf[t];
    float4 cv = ((const float4*)C)[(size_t)idx * 32 + d4];
    float4 zv = ((const float4*)Z)[gid];
    float dx = cv.x - zv.x, dy = cv.y - zv.y, dz = cv.z - zv.z, dw = cv.w - zv.w;
    float4 o;
    o.x = zv.x + dx;    // z + (z_q - z): match reference elementwise rounding
    o.y = zv.y + dy;
    o.z = zv.z + dz;
    o.w = zv.w + dw;
    ((float4*)out)[gid] = o;

    float ls = dx * dx + dy * dy + dz * dz + dw * dw;
#pragma unroll
    for (int off = 32; off > 0; off >>= 1) ls += __shfl_down(ls, off, 64);
    __shared__ float red[4];
    int lane = threadIdx.x & 63, w = threadIdx.x >> 6;
    if (lane == 0) red[w] = ls;
    __syncthreads();
    if (threadIdx.x == 0) {
        atomicAdd(loss, (red[0] + red[1]) + (red[2] + red[3]));
    }
}

// ---------------- scalars: commit_loss, perplexity ----------------
__global__ __launch_bounds__(256) void scalars_kernel(const int* __restrict__ counts,
                                                      const float* __restrict__ loss,
                                                      float* __restrict__ out) {
    float s = 0.f;
    for (int i = threadIdx.x; i < K_CODE; i += 256) {
        float e = (float)counts[i] * (1.0f / (float)T_TOK);
        s += e * logf(e + 1e-8f);
    }
#pragma unroll
    for (int off = 32; off > 0; off >>= 1) s += __shfl_down(s, off, 64);
    __shared__ float red[4];
    int lane = threadIdx.x & 63, w = threadIdx.x >> 6;
    if (lane == 0) red[w] = s;
    __syncthreads();
    if (threadIdx.x == 0) {
        float ssum = (red[0] + red[1]) + (red[2] + red[3]);
        out[(size_t)T_TOK * D_DIM + 0] = 1.25f * loss[0] / (float)((size_t)T_TOK * D_DIM);
        out[(size_t)T_TOK * D_DIM + 1] = expf(-ssum);
    }
}

extern "C" void kernel_launch(void* const* d_in, const int* in_sizes, int n_in,
                              void* d_out, int out_size, void* d_ws, size_t ws_size,
                              hipStream_t stream) {
    const float* z   = (const float*)d_in[0];   // [8,4096,128]
    const float* emb = (const float*)d_in[1];   // [8192,128]
    const float* pw  = (const float*)d_in[2];   // [128,128]
    const float* pb  = (const float*)d_in[3];   // [128]
    float* out = (float*)d_out;

    char* ws = (char*)d_ws;
    float* C      = (float*)(ws + 0);
    float* cn     = (float*)(ws + 4194304);
    float* zn     = (float*)(ws + 4227072);
    ull*   packed = (ull*)  (ws + 4358144);
    int*   idxf   = (int*)  (ws + 4620288);
    int*   counts = (int*)  (ws + 4751360);
    float* loss   = (float*)(ws + 4784128);

    hipMemsetAsync(packed, 0xFF, (size_t)T_TOK * 8, stream);
    hipMemsetAsync(counts, 0, K_CODE * 4 + 4, stream);   // counts + loss

    proj_kernel<<<(K_CODE * D_DIM) / 256, 256, 0, stream>>>(emb, pw, pb, C);
    cnorm_kernel<<<K_CODE, 64, 0, stream>>>(C, cn);
    znorm_kernel<<<T_TOK, 64, 0, stream>>>(z, zn);
    argmin_kernel<<<dim3(T_TOK / BM, NSPLIT), 256, 0, stream>>>(z, C, cn, zn, packed);
    merge_kernel<<<T_TOK / 256, 256, 0, stream>>>(packed, idxf, counts);
    zq_kernel<<<(T_TOK * D_DIM / 4) / 256, 256, 0, stream>>>(z, C, idxf, out, loss);
    scalars_kernel<<<1, 256, 0, stream>>>(counts, loss, out);
}

// Round 6
// 1027.687 us; speedup vs baseline: 2.3056x; 1.0602x over previous
//
#include <hip/hip_runtime.h>
#include <math.h>

#define T_TOK 32768
#define D_DIM 128
#define K_CODE 8192
#define BM 256              // tokens per block
#define BN 64               // codes per block
#define NSPLIT (K_CODE / BN)

typedef unsigned long long ull;

// ---------------- proj: C[r][c] = sum_d E[r][d]*W[c][d] + b[c] ----------------
__global__ __launch_bounds__(256) void proj_kernel(const float* __restrict__ E,
                                                   const float* __restrict__ W,
                                                   const float* __restrict__ b,
                                                   float* __restrict__ C) {
    int idx = blockIdx.x * 256 + threadIdx.x;   // r*128 + c
    int r = idx >> 7, c = idx & 127;
    const float4* E4 = (const float4*)(E + (size_t)r * D_DIM);
    const float4* W4 = (const float4*)(W + (size_t)c * D_DIM);
    float4 acc = make_float4(0.f, 0.f, 0.f, 0.f);
#pragma unroll
    for (int dd = 0; dd < 32; ++dd) {
        float4 e = E4[dd], w = W4[dd];
        acc.x = fmaf(e.x, w.x, acc.x);
        acc.y = fmaf(e.y, w.y, acc.y);
        acc.z = fmaf(e.z, w.z, acc.z);
        acc.w = fmaf(e.w, w.w, acc.w);
    }
    C[idx] = ((acc.x + acc.y) + (acc.z + acc.w)) + b[c];
}

// ---------------- cnorm: |c_k|^2 (bit-identical to R5) ----------------
__global__ __launch_bounds__(64) void cnorm_kernel(const float* __restrict__ C,
                                                   float* __restrict__ cn) {
    int r = blockIdx.x;
    int l = threadIdx.x;
    float a = C[r * D_DIM + l];
    float b2 = C[r * D_DIM + 64 + l];
    float s = a * a + b2 * b2;
#pragma unroll
    for (int off = 32; off > 0; off >>= 1) s += __shfl_down(s, off, 64);
    if (l == 0) cn[r] = s;
}

// ---------------- znorm: |z_t|^2 (bit-identical to R5) ----------------
__global__ __launch_bounds__(64) void znorm_kernel(const float* __restrict__ Z,
                                                   float* __restrict__ zn) {
    int t = blockIdx.x;
    int l = threadIdx.x;
    float a = Z[(size_t)t * D_DIM + l];
    float b2 = Z[(size_t)t * D_DIM + 64 + l];
    float s = a * a + b2 * b2;
#pragma unroll
    for (int off = 32; off > 0; off >>= 1) s += __shfl_down(s, off, 64);
    if (l == 0) zn[t] = s;
}

// ---------------- transpose Z -> ZT[d][t] (ZT lives in d_out, dead until zq) --
__global__ __launch_bounds__(256) void transpose_kernel(const float* __restrict__ Z,
                                                        float* __restrict__ ZT) {
    __shared__ float tile[64][133];   // stride 133: 2-way on read phase (free)
    int tid = threadIdx.x;
    int tb = blockIdx.x * 64;
    const float4* Z4 = (const float4*)Z;
#pragma unroll
    for (int it = 0; it < 8; ++it) {
        int idx = it * 256 + tid;     // 0..2047
        int t = idx >> 5, f4 = idx & 31;
        float4 v = Z4[(size_t)(tb + t) * 32 + f4];
        tile[t][4 * f4 + 0] = v.x;
        tile[t][4 * f4 + 1] = v.y;
        tile[t][4 * f4 + 2] = v.z;
        tile[t][4 * f4 + 3] = v.w;
    }
    __syncthreads();
    float4* ZT4 = (float4*)ZT;
#pragma unroll
    for (int it = 0; it < 8; ++it) {
        int idx = it * 256 + tid;     // 0..2047
        int d = idx >> 4, t4 = idx & 15;
        float4 v = make_float4(tile[4 * t4 + 0][d], tile[4 * t4 + 1][d],
                               tile[4 * t4 + 2][d], tile[4 * t4 + 3][d]);
        ZT4[(size_t)d * (T_TOK / 4) + (tb >> 2) + t4] = v;
    }
}

// ---------------- GEMM-style argmin, barrier-free K-loop ----------------
// A-frag: coalesced global b128 from ZT (L1/L2-resident, vmcnt-pipelined by
// the compiler). B tile: staged in LDS ONCE (full depth), read via broadcast
// b128. The 128-step k-loop has no __syncthreads at all (R5 failure: 8
// barriers/block exposed staging latency -> 34% idle).
__global__ __launch_bounds__(256, 4) void argmin_kernel(const float* __restrict__ ZT,
                                                        const float* __restrict__ C,
                                                        const float* __restrict__ cn,
                                                        const float* __restrict__ zn,
                                                        ull* __restrict__ packed) {
    __shared__ float Bs[D_DIM][BN];   // 128 x 64 = 32 KB

    int tid = threadIdx.x;
    int lane = tid & 63;
    int wid = __builtin_amdgcn_readfirstlane(tid >> 6);
    int nb = blockIdx.x * BN;         // x = codes: consecutive blocks share mb
    int mb = blockIdx.y * BM;         //   -> same ZT slice hot in L2
    int n0 = nb + wid * 16;

    // ---- stage whole-depth B tile once ----
    const float4* C4 = (const float4*)C;
#pragma unroll
    for (int it = 0; it < 8; ++it) {
        int idx = it * 256 + tid;     // 0..2047
        int n = idx & 63;
        int f4 = idx >> 6;            // 0..31
        float4 v = C4[(size_t)(nb + n) * 32 + f4];
        Bs[4 * f4 + 0][n] = v.x;
        Bs[4 * f4 + 1][n] = v.y;
        Bs[4 * f4 + 2][n] = v.z;
        Bs[4 * f4 + 3][n] = v.w;
    }
    __syncthreads();

    float acc[4][16];
#pragma unroll
    for (int i = 0; i < 4; ++i)
#pragma unroll
        for (int j = 0; j < 16; ++j) acc[i][j] = 0.f;

    const float4* ZT4 = (const float4*)ZT;
    int zt_off = (mb >> 2) + lane;

#pragma unroll 4
    for (int k = 0; k < D_DIM; ++k) {
        float4 av = ZT4[(size_t)k * (T_TOK / 4) + zt_off];
        const float* bp = &Bs[k][wid * 16];
        float4 b0 = *(const float4*)(bp + 0);
        float4 b1 = *(const float4*)(bp + 4);
        float4 b2 = *(const float4*)(bp + 8);
        float4 b3 = *(const float4*)(bp + 12);
        float bj[16] = {b0.x, b0.y, b0.z, b0.w, b1.x, b1.y, b1.z, b1.w,
                        b2.x, b2.y, b2.z, b2.w, b3.x, b3.y, b3.z, b3.w};
#pragma unroll
        for (int j = 0; j < 16; ++j) {
            acc[0][j] = fmaf(av.x, bj[j], acc[0][j]);
            acc[1][j] = fmaf(av.y, bj[j], acc[1][j]);
            acc[2][j] = fmaf(av.z, bj[j], acc[2][j]);
            acc[3][j] = fmaf(av.w, bj[j], acc[3][j]);
        }
    }

    // ---- epilogue: per-token argmin over this block's 64 codes ----
    int t0 = mb + 4 * lane;
    float4 znv = *(const float4*)&zn[t0];
    float zni[4] = {znv.x, znv.y, znv.z, znv.w};

    float bb[4];
    int   bi4[4];
#pragma unroll
    for (int i = 0; i < 4; ++i) {
        float best = 3.4e38f;
        int bidx = n0;
#pragma unroll
        for (int j = 0; j < 16; ++j) {
            // Match reference rounding: (|z|^2 + |c|^2) - 2*dot, elementwise fp32.
            float s = (zni[i] + cn[n0 + j]) - 2.f * acc[i][j];
            if (s < best) { best = s; bidx = n0 + j; }
        }
        bb[i] = best;
        bi4[i] = bidx;
    }

    __syncthreads();   // k-loop done in all waves before reusing Bs as scratch
    float* rb = &Bs[0][0];            // 4 x 256 floats
    int*   ri = (int*)(&Bs[0][0]) + 1024;
    *(float4*)&rb[wid * BM + 4 * lane] = make_float4(bb[0], bb[1], bb[2], bb[3]);
    *(int4*)&ri[wid * BM + 4 * lane] = make_int4(bi4[0], bi4[1], bi4[2], bi4[3]);
    __syncthreads();

    // one token per thread: reduce 4 waves (ascending wid = ascending code)
    {
        float best = rb[0 * BM + tid];
        int bidx = ri[0 * BM + tid];
#pragma unroll
        for (int w = 1; w < 4; ++w) {
            float v = rb[w * BM + tid];
            int i2 = ri[w * BM + tid];
            if (v < best) { best = v; bidx = i2; }
        }
        // d > 0 always, so f32 bits are monotone as uint; idx in low bits ->
        // ties resolve to smallest idx (first-min, matches argmin).
        ull pk = ((ull)__float_as_uint(best) << 32) | (unsigned)bidx;
        atomicMin(&packed[mb + tid], pk);
    }
}

// ---------------- zq (+ fused merge): unpack winner, gather, counts, loss ----
__global__ __launch_bounds__(256) void zq_kernel(const float* __restrict__ Z,
                                                 const float* __restrict__ C,
                                                 const ull* __restrict__ packed,
                                                 float* __restrict__ out,
                                                 int* __restrict__ counts,
                                                 float* __restrict__ loss) {
    int gid = blockIdx.x * 256 + threadIdx.x;   // over T*D/4 float4s
    int t = gid >> 5;                           // 32 float4 per token
    int d4 = gid & 31;
    int idx = (int)(packed[t] & 0xFFFFFFFFull);
    if (d4 == 0) atomicAdd(&counts[idx], 1);
    float4 cv = ((const float4*)C)[(size_t)idx * 32 + d4];
    float4 zv = ((const float4*)Z)[gid];
    float dx = cv.x - zv.x, dy = cv.y - zv.y, dz = cv.z - zv.z, dw = cv.w - zv.w;
    float4 o;
    o.x = zv.x + dx;    // z + (z_q - z): match reference elementwise rounding
    o.y = zv.y + dy;
    o.z = zv.z + dz;
    o.w = zv.w + dw;
    ((float4*)out)[gid] = o;

    float ls = dx * dx + dy * dy + dz * dz + dw * dw;
#pragma unroll
    for (int off = 32; off > 0; off >>= 1) ls += __shfl_down(ls, off, 64);
    __shared__ float red[4];
    int lane = threadIdx.x & 63, w = threadIdx.x >> 6;
    if (lane == 0) red[w] = ls;
    __syncthreads();
    if (threadIdx.x == 0) {
        atomicAdd(loss, (red[0] + red[1]) + (red[2] + red[3]));
    }
}

// ---------------- scalars: commit_loss, perplexity ----------------
__global__ __launch_bounds__(256) void scalars_kernel(const int* __restrict__ counts,
                                                      const float* __restrict__ loss,
                                                      float* __restrict__ out) {
    float s = 0.f;
    for (int i = threadIdx.x; i < K_CODE; i += 256) {
        float e = (float)counts[i] * (1.0f / (float)T_TOK);
        s += e * logf(e + 1e-8f);
    }
#pragma unroll
    for (int off = 32; off > 0; off >>= 1) s += __shfl_down(s, off, 64);
    __shared__ float red[4];
    int lane = threadIdx.x & 63, w = threadIdx.x >> 6;
    if (lane == 0) red[w] = s;
    __syncthreads();
    if (threadIdx.x == 0) {
        float ssum = (red[0] + red[1]) + (red[2] + red[3]);
        out[(size_t)T_TOK * D_DIM + 0] = 1.25f * loss[0] / (float)((size_t)T_TOK * D_DIM);
        out[(size_t)T_TOK * D_DIM + 1] = expf(-ssum);
    }
}

extern "C" void kernel_launch(void* const* d_in, const int* in_sizes, int n_in,
                              void* d_out, int out_size, void* d_ws, size_t ws_size,
                              hipStream_t stream) {
    const float* z   = (const float*)d_in[0];   // [8,4096,128]
    const float* emb = (const float*)d_in[1];   // [8192,128]
    const float* pw  = (const float*)d_in[2];   // [128,128]
    const float* pb  = (const float*)d_in[3];   // [128]
    float* out = (float*)d_out;

    // ZT (transposed z, 16 MB) lives in d_out: dead scratch until zq_kernel
    // overwrites d_out with the final z_q_st (scalars tail written after).
    float* ZT = out;

    char* ws = (char*)d_ws;
    // layout (bytes):
    //   C:      0        .. 4194304   (8192*128 f32)
    //   cn:     4194304  .. 4227072   (8192 f32)
    //   zn:     4227072  .. 4358144   (32768 f32)
    //   packed: 4358144  .. 4620288   (32768 u64)
    //   counts: 4620288  .. 4653056   (8192 i32)
    //   loss:   4653056  .. 4653060   (1 f32)
    float* C      = (float*)(ws + 0);
    float* cn     = (float*)(ws + 4194304);
    float* zn     = (float*)(ws + 4227072);
    ull*   packed = (ull*)  (ws + 4358144);
    int*   counts = (int*)  (ws + 4620288);
    float* loss   = (float*)(ws + 4653056);

    hipMemsetAsync(packed, 0xFF, (size_t)T_TOK * 8, stream);
    hipMemsetAsync(counts, 0, K_CODE * 4 + 4, stream);   // counts + loss

    proj_kernel<<<(K_CODE * D_DIM) / 256, 256, 0, stream>>>(emb, pw, pb, C);
    cnorm_kernel<<<K_CODE, 64, 0, stream>>>(C, cn);
    transpose_kernel<<<T_TOK / 64, 256, 0, stream>>>(z, ZT);
    znorm_kernel<<<T_TOK, 64, 0, stream>>>(z, zn);
    argmin_kernel<<<dim3(NSPLIT, T_TOK / BM), 256, 0, stream>>>(ZT, C, cn, zn, packed);
    zq_kernel<<<(T_TOK * D_DIM / 4) / 256, 256, 0, stream>>>(z, C, packed, out, counts, loss);
    scalars_kernel<<<1, 256, 0, stream>>>(counts, loss, out);
}